// Round 1
// 704.419 us; speedup vs baseline: 1.3877x; 1.3877x over previous
//
#include <hip/hip_runtime.h>
#include <hip/hip_bf16.h>
#include <cstdint>

typedef __attribute__((ext_vector_type(8))) short short8;
typedef __attribute__((ext_vector_type(4))) float floatx4;
typedef __attribute__((ext_vector_type(16))) float floatx16;

#define Bdim 32
#define Tdim 48
#define Ldim 400
#define Hdim 512
#define Edim 128
#define Vdim 50000
#define VEdim 50100
#define BTdim 1536
#define CATdim 1536
#define NPAD 50048     // 782*64; also 391*128
#define MTILES 96      // BTdim/16
#define NPART 782      // 64-col tiles in pass 1
#define NPSTRIDE 800   // padded row stride of partial[m][wid]

__device__ __forceinline__ short f2bf(float x){
    __hip_bfloat16 h = __float2bfloat16(x);
    union { __hip_bfloat16 h; short s; } u; u.h = h; return u.s;
}

// ---------------- fp32 tiled GEMM body, C = A(MxK) @ B(KxN), row-major ----
// register double-buffer: next global tile loads issue under the inner product
__device__ __forceinline__ void gemm_nn_body(
    const float* __restrict__ A, int lda,
    const float* __restrict__ B, int ldb,
    float* __restrict__ C, int ldc,
    int M, int N, int K, int m0, int n0)
{
    __shared__ float As[16][68];
    __shared__ float Bs[16][68];
    const int tid = threadIdx.x;
    const int tx = tid & 15, ty = tid >> 4;
    const int ar = tid >> 2, ac = (tid & 3) * 4;   // A: row in tile, col*4
    const int br = tid >> 4, bc = (tid & 15) * 4;  // B: row in tile, col*4
    float acc[4][4] = {};
    float4 va = make_float4(0.f,0.f,0.f,0.f);
    float4 vb = make_float4(0.f,0.f,0.f,0.f);
    if (m0 + ar < M) va = *(const float4*)(A + (size_t)(m0+ar)*lda + ac);
    if (n0 + bc < N) vb = *(const float4*)(B + (size_t)br*ldb + n0 + bc);
    for (int k0 = 0; k0 < K; k0 += 16){
        As[ac+0][ar]=va.x; As[ac+1][ar]=va.y; As[ac+2][ar]=va.z; As[ac+3][ar]=va.w;
        Bs[br][bc+0]=vb.x; Bs[br][bc+1]=vb.y; Bs[br][bc+2]=vb.z; Bs[br][bc+3]=vb.w;
        __syncthreads();
        const int kn = k0 + 16;
        if (kn < K){
            va = make_float4(0.f,0.f,0.f,0.f);
            vb = make_float4(0.f,0.f,0.f,0.f);
            if (m0 + ar < M) va = *(const float4*)(A + (size_t)(m0+ar)*lda + kn + ac);
            if (n0 + bc < N) vb = *(const float4*)(B + (size_t)(kn+br)*ldb + n0 + bc);
        }
        #pragma unroll
        for (int k=0;k<16;k++){
            float a[4], b[4];
            #pragma unroll
            for (int i=0;i<4;i++) a[i] = As[k][ty*4+i];
            #pragma unroll
            for (int j=0;j<4;j++) b[j] = Bs[k][tx*4+j];
            #pragma unroll
            for (int i=0;i<4;i++)
                #pragma unroll
                for (int j=0;j<4;j++)
                    acc[i][j] += a[i]*b[j];
        }
        __syncthreads();
    }
    #pragma unroll
    for (int i=0;i<4;i++){
        int m = m0 + ty*4 + i;
        if (m >= M) continue;
        #pragma unroll
        for (int j=0;j<4;j++){
            int n = n0 + tx*4 + j;
            if (n < N) C[(size_t)m*ldc + n] = acc[i][j];
        }
    }
}

// ---------------- fp32 tiled GEMM body, C = A(MxK) @ B(NxK)^T -------------
__device__ __forceinline__ void gemm_nt_body(
    const float* __restrict__ A, int lda,
    const float* __restrict__ B, int ldb,
    float* __restrict__ C, int ldc,
    int M, int N, int K, int m0, int n0)
{
    __shared__ float As[16][68];
    __shared__ float Bs[16][68];
    const int tid = threadIdx.x;
    const int tx = tid & 15, ty = tid >> 4;
    const int r = tid >> 2, c = (tid & 3) * 4;
    float acc[4][4] = {};
    float4 va = make_float4(0.f,0.f,0.f,0.f);
    float4 vb = make_float4(0.f,0.f,0.f,0.f);
    if (m0 + r < M) va = *(const float4*)(A + (size_t)(m0+r)*lda + c);
    if (n0 + r < N) vb = *(const float4*)(B + (size_t)(n0+r)*ldb + c);
    for (int k0 = 0; k0 < K; k0 += 16){
        As[c+0][r]=va.x; As[c+1][r]=va.y; As[c+2][r]=va.z; As[c+3][r]=va.w;
        Bs[c+0][r]=vb.x; Bs[c+1][r]=vb.y; Bs[c+2][r]=vb.z; Bs[c+3][r]=vb.w;
        __syncthreads();
        const int kn = k0 + 16;
        if (kn < K){
            va = make_float4(0.f,0.f,0.f,0.f);
            vb = make_float4(0.f,0.f,0.f,0.f);
            if (m0 + r < M) va = *(const float4*)(A + (size_t)(m0+r)*lda + kn + c);
            if (n0 + r < N) vb = *(const float4*)(B + (size_t)(n0+r)*ldb + kn + c);
        }
        #pragma unroll
        for (int k=0;k<16;k++){
            float a[4], b[4];
            #pragma unroll
            for (int i=0;i<4;i++) a[i] = As[k][ty*4+i];
            #pragma unroll
            for (int j=0;j<4;j++) b[j] = Bs[k][tx*4+j];
            #pragma unroll
            for (int i=0;i<4;i++)
                #pragma unroll
                for (int j=0;j<4;j++)
                    acc[i][j] += a[i]*b[j];
        }
        __syncthreads();
    }
    #pragma unroll
    for (int i=0;i<4;i++){
        int m = m0 + ty*4 + i;
        if (m >= M) continue;
        #pragma unroll
        for (int j=0;j<4;j++){
            int n = n0 + tx*4 + j;
            if (n < N) C[(size_t)m*ldc + n] = acc[i][j];
        }
    }
}

// ---------------- merged P1/P2 (shared A = dec) ---------------------------
__global__ __launch_bounds__(256) void k_p12(
    const float* __restrict__ dec, const float* __restrict__ Wenc,
    const float* __restrict__ Wdec, float* __restrict__ P1, float* __restrict__ P2)
{
    const float* B = blockIdx.z ? Wdec : Wenc;
    float* C = blockIdx.z ? P2 : P1;
    gemm_nn_body(dec, Hdim, B, Hdim, C, Hdim, BTdim, Hdim, Hdim,
                 blockIdx.y*64, blockIdx.x*64);
}

// ---------------- merged e-scores / s-scores (both NT, K=512) -------------
__global__ __launch_bounds__(256) void k_es(
    const float* __restrict__ P1, const float* __restrict__ P2,
    const float* __restrict__ enc, const float* __restrict__ dec,
    float* __restrict__ ebuf, float* __restrict__ sbuf)
{
    int z = blockIdx.z;
    if (z < 32){
        gemm_nt_body(P1 + (size_t)z*Tdim*Hdim, Hdim,
                     enc + (size_t)z*Ldim*Hdim, Hdim,
                     ebuf + (size_t)z*Tdim*Ldim, Ldim,
                     Tdim, Ldim, Hdim, 0, blockIdx.x*64);
    } else {
        if (blockIdx.x) return;
        z -= 32;
        gemm_nt_body(P2 + (size_t)z*Tdim*Hdim, Hdim,
                     dec + (size_t)z*Tdim*Hdim, Hdim,
                     sbuf + (size_t)z*Tdim*Tdim, Tdim,
                     Tdim, Tdim, Hdim, 0, 0);
    }
}

// ------------- merged: temporal prefix scan + masked decoder softmax ------
__global__ __launch_bounds__(256) void k_tempdec(
    const float* __restrict__ e, float* __restrict__ att, float* __restrict__ sbuf)
{
    int bid = blockIdx.x;
    if (bid < 50){
        int idx = bid*256 + threadIdx.x;
        if (idx >= Bdim * Ldim) return;
        int b = idx / Ldim, l = idx % Ldim;
        const float* ep = e + (size_t)b * Tdim * Ldim + l;
        float* ap = att + (size_t)b * Tdim * Ldim + l;
        float acc = 0.f;
        for (int t = 0; t < Tdim; ++t){
            float x = __expf(ep[(size_t)t * Ldim]);
            float d = (t == 0) ? 1.f : acc;
            ap[(size_t)t * Ldim] = x / d;
            acc += x;
        }
    } else {
        int b = bid - 50;
        int t = threadIdx.x;
        if (t >= Tdim) return;
        float* row = sbuf + (size_t)b * Tdim * Tdim + (size_t)t * Tdim;
        if (t == 0){
            for (int j = 0; j < Tdim; ++j) row[j] = 0.f;  // dec_ctx forced 0 at t=0
            return;
        }
        float mx = -1e30f;
        for (int j = 0; j < t; ++j) mx = fmaxf(mx, row[j]);
        float sum = 0.f;
        for (int j = 0; j < t; ++j){ float ex = __expf(row[j]-mx); row[j]=ex; sum+=ex; }
        float inv = 1.f/sum;
        for (int j = 0; j < t; ++j) row[j] *= inv;
        for (int j = t; j < Tdim; ++j) row[j] = 0.f;
    }
}

// ------------- normalize temporal over l (in place) ------------------------
__global__ __launch_bounds__(256) void k_attnorm(float* __restrict__ att){
    int row = blockIdx.x;  // b*T + t
    float* ap = att + (size_t)row * Ldim;
    float s = 0.f;
    for (int i = threadIdx.x; i < Ldim; i += 256) s += ap[i];
    #pragma unroll
    for (int off = 32; off; off >>= 1) s += __shfl_down(s, off, 64);
    __shared__ float red[4];
    if ((threadIdx.x & 63) == 0) red[threadIdx.x >> 6] = s;
    __syncthreads();
    float inv = 1.f / (red[0] + red[1] + red[2] + red[3]);
    for (int i = threadIdx.x; i < Ldim; i += 256) ap[i] *= inv;
}

// ------------- merged: enc_ctx GEMM + dec_ctx GEMM + h copy ---------------
__global__ __launch_bounds__(256) void k_ctx(
    const float* __restrict__ att, const float* __restrict__ sbuf,
    const float* __restrict__ enc, const float* __restrict__ dec,
    float* __restrict__ cat)
{
    int z = blockIdx.z;
    if (z >= 64){
        // copy h into cat[:, 0:512], float4
        int idx = ((z-64)*8 + blockIdx.x)*256 + threadIdx.x;  // 0..196607
        int m = idx >> 7, j = (idx & 127) << 2;
        *(float4*)(cat + (size_t)m*CATdim + j) =
            *(const float4*)(dec + (size_t)m*Hdim + j);
        return;
    }
    const float *A, *Bm; float* C; int lda, K;
    if (z < 32){
        A = att + (size_t)z*Tdim*Ldim; lda = Ldim;
        Bm = enc + (size_t)z*Ldim*Hdim;
        C = cat + (size_t)z*Tdim*CATdim + Hdim;
        K = Ldim;
    } else {
        int b = z - 32;
        A = sbuf + (size_t)b*Tdim*Tdim; lda = Tdim;
        Bm = dec + (size_t)b*Tdim*Hdim;
        C = cat + (size_t)b*Tdim*CATdim + 2*Hdim;
        K = Tdim;
    }
    gemm_nn_body(A, lda, Bm, Hdim, C, CATdim, Tdim, Hdim, K, 0, blockIdx.x*64);
}

// ------------- projection GEMM (split-K x4 over z) ------------------------
__global__ __launch_bounds__(256) void k_proj(
    const float* __restrict__ cat, const float* __restrict__ Wproj,
    float* __restrict__ projf4)
{
    int z = blockIdx.z;
    gemm_nn_body(cat + (size_t)z*384, CATdim,
                 Wproj + (size_t)z*384*Edim, Edim,
                 projf4 + (size_t)z*BTdim*Edim, Edim,
                 BTdim, Edim, 384, blockIdx.y*64, blockIdx.x*64);
}

// ------------- merged: pgate + proj->bf16 + W_vocab transpose->bf16 -------
__global__ __launch_bounds__(256) void k_post(
    const float* __restrict__ cat, const float* __restrict__ wp,
    const float* __restrict__ bp, float* __restrict__ pg,
    const float* __restrict__ pf, short* __restrict__ pb,
    const float* __restrict__ Wv, short* __restrict__ Wt)
{
    __shared__ float smem[32*33];
    int bid = blockIdx.x;
    if (bid < BTdim){
        // pointer gate
        const float* cp = cat + (size_t)bid*CATdim;
        float s = 0.f;
        for (int i=threadIdx.x;i<CATdim;i+=256) s += cp[i]*wp[i];
        #pragma unroll
        for (int off=32; off; off>>=1) s += __shfl_down(s, off, 64);
        if ((threadIdx.x&63)==0) smem[threadIdx.x>>6]=s;
        __syncthreads();
        if (threadIdx.x==0){
            float tot = smem[0]+smem[1]+smem[2]+smem[3] + bp[0];
            pg[bid] = 1.f/(1.f + __expf(-tot));
        }
        return;
    }
    if (bid < BTdim + 768){
        // proj split-K partial sum -> bf16
        int i = (bid - BTdim)*256 + threadIdx.x;   // 0..196607
        pb[i] = f2bf(pf[i] + pf[i + 196608] + pf[i + 2*196608] + pf[i + 3*196608]);
        return;
    }
    // W_vocab (128 x 50000) -> bf16 transposed (50048 x 128)
    int b2 = bid - (BTdim + 768);                  // 0..6255
    int n0 = (b2 % 1564)*32, k0 = (b2 / 1564)*32;
    float (*tile)[33] = reinterpret_cast<float(*)[33]>(smem);
    int x = threadIdx.x & 31, y0 = threadIdx.x >> 5;  // 32 x 8
    for (int yy=y0; yy<32; yy+=8){
        int n = n0 + x;
        tile[yy][x] = (n < Vdim) ? Wv[(size_t)(k0+yy)*Vdim + n] : 0.f;
    }
    __syncthreads();
    for (int yy=y0; yy<32; yy+=8){
        int n = n0 + yy;
        if (n < NPAD) Wt[(size_t)n*Edim + k0 + x] = f2bf(tile[x][yy]);
    }
}

// ------------- logits pass 1: per-row sum(exp) ----------------------------
// Swapped-operand 16x16x32 MFMA: mfma(B,A) makes the row index m lane-local
// (m = lane&15), so the 64-col sum needs only 2 shfl_xor stages (over quads).
// Each wave covers 64 vocab cols (4 col-tiles sharing the A fragment), with
// a 2-deep manual prefetch of the A fragments. Partial stored transposed
// [m][wid] (stride NPSTRIDE) so k_reduce reads coalesced rows.
__global__ __launch_bounds__(256) void k_logits1(
    const short* __restrict__ Ab, const short* __restrict__ Bt,
    float* __restrict__ partial)
{
    const int lane = threadIdx.x & 63;
    const int wave = threadIdx.x >> 6;
    const int l15 = lane & 15, quad = lane >> 4;
    const int wid = blockIdx.x*4 + wave;
    if (wid >= NPART) return;
    const int n0 = wid*64;
    short8 bfrag[4][4];
    #pragma unroll
    for (int ct=0;ct<4;ct++){
        const short* bp = Bt + (size_t)(n0 + ct*16 + l15)*Edim + quad*8;
        #pragma unroll
        for (int kk=0;kk<4;kk++) bfrag[ct][kk] = *(const short8*)(bp + kk*32);
    }
    float vmask[4];
    #pragma unroll
    for (int ct=0;ct<4;ct++) vmask[ct] = (n0 + ct*16 < Vdim) ? 1.f : 0.f;

    auto loadA = [&](int mt, short8 (&af)[4]){
        const short* ap = Ab + (size_t)(mt*16 + l15)*Edim + quad*8;
        #pragma unroll
        for (int kk=0;kk<4;kk++) af[kk] = *(const short8*)(ap + kk*32);
    };
    auto compute = [&](int mt, short8 (&af)[4]){
        floatx4 a0 = {0.f,0.f,0.f,0.f};
        floatx4 a1 = a0, a2 = a0, a3 = a0;
        #pragma unroll
        for (int kk=0;kk<4;kk++){
            a0 = __builtin_amdgcn_mfma_f32_16x16x32_bf16(bfrag[0][kk], af[kk], a0, 0, 0, 0);
            a1 = __builtin_amdgcn_mfma_f32_16x16x32_bf16(bfrag[1][kk], af[kk], a1, 0, 0, 0);
            a2 = __builtin_amdgcn_mfma_f32_16x16x32_bf16(bfrag[2][kk], af[kk], a2, 0, 0, 0);
            a3 = __builtin_amdgcn_mfma_f32_16x16x32_bf16(bfrag[3][kk], af[kk], a3, 0, 0, 0);
        }
        float s = vmask[0]*(__expf(a0[0])+__expf(a0[1])+__expf(a0[2])+__expf(a0[3]))
                + vmask[1]*(__expf(a1[0])+__expf(a1[1])+__expf(a1[2])+__expf(a1[3]))
                + vmask[2]*(__expf(a2[0])+__expf(a2[1])+__expf(a2[2])+__expf(a2[3]))
                + vmask[3]*(__expf(a3[0])+__expf(a3[1])+__expf(a3[2])+__expf(a3[3]));
        s += __shfl_xor(s, 16, 64);
        s += __shfl_xor(s, 32, 64);
        if (lane < 16)
            partial[(size_t)(mt*16 + l15)*NPSTRIDE + wid] = s;
    };

    short8 afA[4], afB[4];
    loadA(0, afA);
    for (int mt=0; mt<MTILES; mt+=2){
        loadA(mt+1, afB);
        compute(mt, afA);
        if (mt+2 < MTILES) loadA(mt+2, afA);
        compute(mt+1, afB);
    }
}

// ------------- reduce per-row partials -> scale = (1-p)/S ------------------
__global__ __launch_bounds__(256) void k_reduce(const float* __restrict__ partial,
                         const float* __restrict__ pg, float* __restrict__ scale){
    int m = blockIdx.x;
    float s = 0.f;
    for (int w = threadIdx.x; w < NPART; w += 256)
        s += partial[(size_t)m*NPSTRIDE + w];
    #pragma unroll
    for (int off=32; off; off>>=1) s += __shfl_down(s, off, 64);
    __shared__ float red[4];
    if ((threadIdx.x&63)==0) red[threadIdx.x>>6]=s;
    __syncthreads();
    if (threadIdx.x==0)
        scale[m] = (1.f - pg[m]) / (red[0]+red[1]+red[2]+red[3]);
}

// ------------- logits pass 2: write (1-p)*softmax, 32x32x16 MFMA -----------
// C layout: col=lane&31, row=(reg&3)+8*(reg>>2)+4*(lane>>5). mt-range split
// over blockIdx.y for CU balance; OOV/pad cols (50000..50099) zero-filled here.
__global__ __launch_bounds__(256) void k_logits2(
    const short* __restrict__ Ab, const short* __restrict__ Bt,
    const float* __restrict__ scale, float* __restrict__ out)
{
    const int lane = threadIdx.x & 63;
    const int wave = threadIdx.x >> 6;
    const int l31 = lane & 31, half = lane >> 5;
    const int n0 = blockIdx.x*128 + wave*32;
    const int n = n0 + l31;
    const int mt0 = blockIdx.y * 24;
    if (n0 >= Vdim){
        if (n < VEdim){
            for (int mt=mt0; mt<mt0+24; ++mt){
                #pragma unroll
                for (int r=0;r<16;r++){
                    int m = mt*32 + (r&3) + 8*(r>>2) + 4*half;
                    out[(size_t)m*VEdim + n] = 0.f;
                }
            }
        }
        return;
    }
    short8 bfrag[8];
    const short* bp = Bt + (size_t)n*Edim + half*8;
    #pragma unroll
    for (int kk=0;kk<8;kk++) bfrag[kk] = *(const short8*)(bp + kk*16);
    const bool valid = n < Vdim;
    for (int mt=mt0; mt<mt0+24; ++mt){
        floatx16 acc;
        #pragma unroll
        for (int i=0;i<16;i++) acc[i] = 0.f;
        const short* ap = Ab + (size_t)(mt*32 + l31)*Edim + half*8;
        #pragma unroll
        for (int kk=0;kk<8;kk++){
            short8 af = *(const short8*)(ap + kk*16);
            acc = __builtin_amdgcn_mfma_f32_32x32x16_bf16(af, bfrag[kk], acc, 0, 0, 0);
        }
        #pragma unroll
        for (int r=0;r<16;r++){
            int m = mt*32 + (r&3) + 8*(r>>2) + 4*half;
            if (valid) out[(size_t)m*VEdim + n] = scale[m]*__expf(acc[r]);
            else if (n < VEdim) out[(size_t)m*VEdim + n] = 0.f;
        }
    }
}

// ------------- pointer scatter-add -----------------------------------------
__global__ void k_scatter(const float* __restrict__ att, const float* __restrict__ pg,
                          const int* __restrict__ ev, float* __restrict__ out){
    int idx = blockIdx.x*256 + threadIdx.x;
    if (idx >= BTdim*Ldim) return;
    int m = idx / Ldim, l = idx % Ldim;
    int b = m / Tdim;
    int v = ev[b*Ldim + l];
    atomicAdd(&out[(size_t)m*VEdim + v], pg[m]*att[idx]);
}

extern "C" void kernel_launch(void* const* d_in, const int* in_sizes, int n_in,
                              void* d_out, int out_size, void* d_ws, size_t ws_size,
                              hipStream_t stream)
{
    const float* dec  = (const float*)d_in[0];
    const float* enc  = (const float*)d_in[1];
    const float* Wenc = (const float*)d_in[2];
    const float* Wdec = (const float*)d_in[3];
    const float* Wproj= (const float*)d_in[4];
    const float* Wvoc = (const float*)d_in[5];
    const float* wptr = (const float*)d_in[6];
    const float* bptr = (const float*)d_in[7];
    const int*   ev   = (const int*)d_in[8];
    float* out = (float*)d_out;

    float* ws = (float*)d_ws;
    float* P1      = ws;                       // 1536x512
    float* P2      = P1 + 786432;              // 1536x512
    float* ebuf    = P2 + 786432;              // 32x48x400
    float* att     = ebuf + 614400;            // 32x48x400
    float* sbuf    = att + 614400;             // 32x48x48
    float* cat     = sbuf + 73728;             // 1536x1536
    float* projf4  = cat + 2359296;            // 4 x 1536x128 (split-K partials)
    float* pg      = projf4 + 4*196608;        // 1536
    float* scale   = pg + 1536;                // 1536
    float* partial = scale + 1536;             // 1536 x NPSTRIDE = 1536x800
    short* projb   = (short*)(partial + (size_t)BTdim*NPSTRIDE);  // 1536x128 bf16
    short* Wt      = projb + 196608;           // 50048x128 bf16

    dim3 blk(256);
    // P1 = dec @ W_enc ; P2 = dec @ W_dec (one launch)
    k_p12<<<dim3(8,24,2), blk, 0, stream>>>(dec, Wenc, Wdec, P1, P2);
    // e[b] = P1_b @ enc_b^T ; s[b] = P2_b @ dec_b^T (one launch)
    k_es<<<dim3(7,1,64), blk, 0, stream>>>(P1, P2, enc, dec, ebuf, sbuf);
    // temporal prefix scan + masked decoder softmax (one launch), then l-norm
    k_tempdec<<<dim3(82), blk, 0, stream>>>(ebuf, att, sbuf);
    k_attnorm<<<dim3(BTdim), blk, 0, stream>>>(att);
    // cat = [h | enc_ctx | dec_ctx] (one launch: 2 GEMMs + copy)
    k_ctx<<<dim3(8,1,160), blk, 0, stream>>>(att, sbuf, enc, dec, cat);
    // projection (split-K x4)
    k_proj<<<dim3(2,24,4), blk, 0, stream>>>(cat, Wproj, projf4);
    // pgate + proj->bf16 + W_vocab transpose (one launch)
    k_post<<<dim3(BTdim + 768 + 6256), blk, 0, stream>>>(cat, wptr, bptr, pg,
                                                         projf4, projb, Wvoc, Wt);
    // vocab GEMM (bf16 MFMA), softmax-fused two-pass
    k_logits1<<<dim3(196), blk, 0, stream>>>(projb, Wt, partial);
    k_reduce<<<dim3(BTdim), blk, 0, stream>>>(partial, pg, scale);
    k_logits2<<<dim3(392,2), blk, 0, stream>>>(projb, Wt, scale, out);
    // pointer scatter
    k_scatter<<<dim3((BTdim*Ldim+255)/256), blk, 0, stream>>>(att, pg, ev, out);
}